// Round 8
// baseline (79.928 us; speedup 1.0000x reference)
//
#include <hip/hip_runtime.h>

#define NN 32
#define MAX_ITERS 10
#define TPB 256

// Projection math validated R1-R7 (bit-exact algebraic form of reference):
//  forward = 31-step prefix-min; backward: q[u] = med3(p[u], max_child, q_fwd[u-1]).
__device__ __forceinline__ void project(float p[NN], float q[NN]) {
    #pragma unroll 1
    for (int it = 0; it < MAX_ITERS; ++it) {
        #pragma unroll
        for (int u = 0; u < NN - 1; ++u)
            q[u + 1] = fminf(q[u + 1], q[u]);
        #pragma unroll
        for (int u = NN - 1; u >= 0; --u) {
            float maxc;
            if (u == NN - 1)      maxc = 0.0f;
            else if (u == NN - 2) maxc = q[NN - 1];
            else                  maxc = fmaxf(q[u + 1], q[u + 2]);
            float minp = (u == 0) ? 1.0f : q[u - 1];
            q[u] = __builtin_amdgcn_fmed3f(p[u], maxc, minp);
        }
    }
}

// ---- A: the real kernel (R1 form, known correct, ~40us baseline) ----
__global__ __launch_bounds__(TPB) void dag_full(
    const float* __restrict__ x, float* __restrict__ out, int brows)
{
    int row = blockIdx.x * blockDim.x + threadIdx.x;
    if (row >= brows) return;
    const float4* xr = reinterpret_cast<const float4*>(x) + (size_t)row * 8;
    float p[NN], q[NN];
    #pragma unroll
    for (int k = 0; k < 8; ++k) {
        float4 v = xr[k];
        p[4*k+0] = v.x; p[4*k+1] = v.y; p[4*k+2] = v.z; p[4*k+3] = v.w;
    }
    #pragma unroll
    for (int i = 0; i < NN; ++i) {
        p[i] = __builtin_amdgcn_rcpf(1.0f + __expf(-p[i]));
        q[i] = p[i];
    }
    project(p, q);
    float4* outr = reinterpret_cast<float4*>(out) + (size_t)row * 8;
    #pragma unroll
    for (int k = 0; k < 8; ++k)
        outr[k] = make_float4(q[4*k+0], q[4*k+1], q[4*k+2], q[4*k+3]);
}

// ---- B: compute probe -- identical VALU/TRANS work, 1/8 memory traffic ----
// One coalesced float4 in, one float4 out (to d_ws). p[] derived per-element
// from loaded data (distinct expressions; no const-folding of the min/max
// network possible). Stored q[0],q[7],q[15],q[31]: the backward chain makes
// q[0] transitively depend on every p/q -> whole network is DCE-live.
__global__ __launch_bounds__(TPB) void dag_compute_probe(
    const float* __restrict__ x, float4* __restrict__ ws, int brows)
{
    int tid = blockIdx.x * blockDim.x + threadIdx.x;
    if (tid >= brows) return;
    float4 v = reinterpret_cast<const float4*>(x)[tid];
    float p[NN], q[NN];
    #pragma unroll
    for (int i = 0; i < NN; ++i) {
        float base = (i & 2) ? ((i & 1) ? v.w : v.z) : ((i & 1) ? v.y : v.x);
        p[i] = base + (float)i * 0.03125f;
    }
    #pragma unroll
    for (int i = 0; i < NN; ++i) {
        p[i] = __builtin_amdgcn_rcpf(1.0f + __expf(-p[i]));
        q[i] = p[i];
    }
    project(p, q);
    ws[tid] = make_float4(q[0], q[7], q[15], q[31]);
}

// ---- C: memory probe -- pure float4 copy of the input footprint ----
__global__ __launch_bounds__(TPB) void copy_probe(
    const float4* __restrict__ src, float4* __restrict__ dst, int n4)
{
    int stride = gridDim.x * blockDim.x;
    for (int i = blockIdx.x * blockDim.x + threadIdx.x; i < n4; i += stride)
        dst[i] = src[i];
}

extern "C" void kernel_launch(void* const* d_in, const int* in_sizes, int n_in,
                              void* d_out, int out_size, void* d_ws, size_t ws_size,
                              hipStream_t stream)
{
    const float* x = (const float*)d_in[0];
    float* out = (float*)d_out;

    int total = in_sizes[0];      // B * N
    int brows = total / NN;       // B rows

    int blocks = (brows + TPB - 1) / TPB;   // 2048

    // A: correct output (validated by harness)
    dag_full<<<blocks, TPB, 0, stream>>>(x, out, brows);

    // B: compute-isolated probe (16B/thread in+out)
    if (ws_size >= (size_t)brows * sizeof(float4))
        dag_compute_probe<<<blocks, TPB, 0, stream>>>(x, (float4*)d_ws, brows);

    // C: bandwidth calibration (copy full input footprint)
    if (ws_size >= (size_t)total * sizeof(float)) {
        int n4 = total / 4;
        copy_probe<<<blocks, TPB, 0, stream>>>(
            (const float4*)x, (float4*)d_ws, n4);
    }
}